// Round 3
// baseline (135.891 us; speedup 1.0000x reference)
//
#include <hip/hip_runtime.h>
#include <stdint.h>

// Problem constants: B=4, I=32, N=4096, D=64, TEM=1.0, WP=0.5
#define Bsz 4
#define Isz 32
#define Nsz 4096
#define Dsz 64
#define WPc 0.5f
#define NT 32      // 128-wide tiles per dimension
#define NPAIR 528  // NT*(NT+1)/2 upper-triangular tile pairs

typedef __attribute__((ext_vector_type(8))) short short8;   // 8 bf16
typedef __attribute__((ext_vector_type(4))) float floatx4;  // MFMA C/D

__device__ inline uint16_t f2bf(float f) {
  uint32_t u = __float_as_uint(f);
  u += 0x7fffu + ((u >> 16) & 1u);  // RNE
  return (uint16_t)(u >> 16);
}

// ---------------------------------------------------------------------------
// Kernel 1 (fused): fp32->bf16 convert (all 1024 blocks) + label decode and
// gpos/gneg/accum/ticket zeroing (blocks 0..63). Stream order makes all of
// this visible to sim/fin without a separate memset dispatch.
// ---------------------------------------------------------------------------
__global__ __launch_bounds__(256) void prep_kernel(
    const float* __restrict__ x, const uint8_t* __restrict__ label,
    uint16_t* __restrict__ xb, int* __restrict__ inst,
    float* __restrict__ gpos, float* __restrict__ gneg,
    float* __restrict__ accum, int* __restrict__ ticket) {
  const int t = threadIdx.x;
  const int blk = blockIdx.x;
  // convert 4 elements
  const int idx4 = (blk * 256 + t) * 4;
  const float4 v = *(const float4*)(x + idx4);
  ushort4 o;
  o.x = f2bf(v.x);
  o.y = f2bf(v.y);
  o.z = f2bf(v.z);
  o.w = f2bf(v.w);
  *(ushort4*)(xb + idx4) = o;

  if (blk < 64) {  // one thread per point: decode label, zero row accumulators
    const int p = blk * 256 + t;  // 0..16383
    const int b = p >> 12;
    const int n = p & (Nsz - 1);
    const uint8_t* lb = label + (size_t)b * Isz * Nsz;
    int id = 0;
#pragma unroll
    for (int i = 0; i < Isz; ++i) {
      if (lb[(size_t)i * Nsz + n]) id = i;
    }
    inst[p] = id;
    gpos[p] = 0.f;
    gneg[p] = 0.f;
    if (p == 0) {
      accum[0] = 0.f;
      ticket[0] = 0;
    }
  }
}

// ---------------------------------------------------------------------------
// Kernel 2: MFMA sim tile + fused epilogue, UPPER-TRIANGULAR tile pairs.
// Block = 4 waves; tile 128x128 of sim = X X^T (K=D=64), fragments direct
// from L2-resident bf16. Each off-diag element contributes to its row sum
// (reduce over l15: xor 1,2,4,8) AND to the transposed row via a column sum
// (reduce over quads: xor 16,32). Diagonal tiles use row sums only.
// C/D layout: col = lane&15, row = (lane>>4)*4 + reg.
// ---------------------------------------------------------------------------
__global__ __launch_bounds__(256) void sim_mfma(
    const uint16_t* __restrict__ xb, const int* __restrict__ inst,
    float* __restrict__ gpos, float* __restrict__ gneg) {
  __shared__ int sIr[128];
  __shared__ int sIc[128];
  __shared__ float sPos[128];
  __shared__ float sNeg[128];
  __shared__ float sPosC[128];
  __shared__ float sNegC[128];

  const int t = threadIdx.x;
  const int lane = t & 63;
  const int w = t >> 6;
  const int quad = lane >> 4;
  const int l15 = lane & 15;

  // triangular decode: blockIdx.x in [0, 528) -> (rtile <= ctile)
  int q = blockIdx.x;
  int rtile = 0;
  while (q >= NT - rtile) {
    q -= NT - rtile;
    ++rtile;
  }
  const int ctile = rtile + q;
  const bool diag = (ctile == rtile);

  const int b = blockIdx.y;
  const int row0 = rtile * 128;
  const int col0 = ctile * 128;
  const size_t bN = (size_t)b * Nsz;

  if (t < 128) {
    sIr[t] = inst[bN + row0 + t];
    sPos[t] = 0.f;
    sNeg[t] = 0.f;
    sPosC[t] = 0.f;
    sNegC[t] = 0.f;
  } else {
    sIc[t - 128] = inst[bN + col0 + (t - 128)];
  }
  __syncthreads();

  const int wrow0 = row0 + w * 32;
  const uint16_t* xbB = xb + bN * Dsz;

  floatx4 acc[2][8];
#pragma unroll
  for (int rt = 0; rt < 2; ++rt)
#pragma unroll
    for (int ct = 0; ct < 8; ++ct) acc[rt][ct] = (floatx4){0.f, 0.f, 0.f, 0.f};

#pragma unroll
  for (int kh = 0; kh < 2; ++kh) {
    const int ko = quad * 8 + kh * 32;
    short8 af[2], bfr[8];
#pragma unroll
    for (int rt = 0; rt < 2; ++rt)
      af[rt] = *(const short8*)(xbB + (size_t)(wrow0 + rt * 16 + l15) * Dsz + ko);
#pragma unroll
    for (int ct = 0; ct < 8; ++ct)
      bfr[ct] = *(const short8*)(xbB + (size_t)(col0 + ct * 16 + l15) * Dsz + ko);
#pragma unroll
    for (int ct = 0; ct < 8; ++ct)
#pragma unroll
      for (int rt = 0; rt < 2; ++rt)
        acc[rt][ct] = __builtin_amdgcn_mfma_f32_16x16x32_bf16(af[rt], bfr[ct],
                                                              acc[rt][ct], 0, 0, 0);
  }

  // ---------------- Epilogue ----------------
  int myc[8];
#pragma unroll
  for (int ct = 0; ct < 8; ++ct) myc[ct] = sIc[ct * 16 + l15];

  float pc[8] = {0, 0, 0, 0, 0, 0, 0, 0};  // column (transposed-row) partials
  float nc[8] = {0, 0, 0, 0, 0, 0, 0, 0};

#pragma unroll
  for (int rt = 0; rt < 2; ++rt) {
    const int rl = w * 32 + rt * 16 + quad * 4;
    int ir[4];
#pragma unroll
    for (int r = 0; r < 4; ++r) ir[r] = sIr[rl + r];
    float ps[4] = {0.f, 0.f, 0.f, 0.f};
    float ng[4] = {0.f, 0.f, 0.f, 0.f};
#pragma unroll
    for (int ct = 0; ct < 8; ++ct) {
      const int ci = myc[ct];
      const floatx4 v = acc[rt][ct];
#pragma unroll
      for (int r = 0; r < 4; ++r) {
        const float s = v[r];
        const float d = s - 1.f;
        const bool same = (ci == ir[r]);
        const float dm = same ? d : 0.f;
        const float sq = dm * d;  // (s-1)^2 if same else 0
        ps[r] += sq;
        pc[ct] += sq;
        const float e = __expf(s);  // TEM == 1.0
        const float en = same ? 0.f : e;
        ng[r] += en;
        nc[ct] += en;
      }
    }
    // row reduce over l15 (bits 0..3)
#pragma unroll
    for (int r = 0; r < 4; ++r) {
      float p = ps[r], g = ng[r];
#pragma unroll
      for (int m = 1; m < 16; m <<= 1) {
        p += __shfl_xor(p, m, 64);
        g += __shfl_xor(g, m, 64);
      }
      if (l15 == 0) {  // unique (w,rt,quad,r) -> unique row
        sPos[rl + r] += p;
        sNeg[rl + r] += g;
      }
    }
  }
  // column reduce over quads (bits 4..5)
#pragma unroll
  for (int ct = 0; ct < 8; ++ct) {
    float p = pc[ct], g = nc[ct];
    p += __shfl_xor(p, 16, 64);
    p += __shfl_xor(p, 32, 64);
    g += __shfl_xor(g, 16, 64);
    g += __shfl_xor(g, 32, 64);
    if (quad == 0) {
      atomicAdd(&sPosC[ct * 16 + l15], p);
      atomicAdd(&sNegC[ct * 16 + l15], g);
    }
  }
  __syncthreads();
  if (t < 128) {
    atomicAdd(&gpos[bN + row0 + t], sPos[t]);
    atomicAdd(&gneg[bN + row0 + t], sNeg[t]);
    if (!diag) {
      atomicAdd(&gpos[bN + col0 + t], sPosC[t]);
      atomicAdd(&gneg[bN + col0 + t], sNegC[t]);
    }
  }
}

// ---------------------------------------------------------------------------
// Kernel 3: finalize. One block per batch; LDS histogram for counts; row
// contributions reduced; device-scope atomic accumulate; ticketed last block
// writes the scalar output.
// ---------------------------------------------------------------------------
__global__ __launch_bounds__(1024) void fin_kernel(
    const float* __restrict__ gpos, const float* __restrict__ gneg,
    const int* __restrict__ inst, float* __restrict__ accum,
    int* __restrict__ ticket, float* __restrict__ out) {
  __shared__ int scnt[Isz];
  __shared__ float red[16];
  const int b = blockIdx.x;
  const int t = threadIdx.x;
  if (t < Isz) scnt[t] = 0;
  __syncthreads();
  const int base = b * Nsz;
  int ids[4];
#pragma unroll
  for (int k = 0; k < 4; ++k) {
    ids[k] = inst[base + t + k * 1024];
    atomicAdd(&scnt[ids[k]], 1);
  }
  __syncthreads();
  float local = 0.f;
#pragma unroll
  for (int k = 0; k < 4; ++k) {
    const int idx = base + t + k * 1024;
    const float c = (float)scnt[ids[k]];
    if (c >= 5.f) {
      const float lp = gpos[idx] / (c * c);
      const float ln = __logf(fmaxf(gneg[idx], 1e-30f)) / c;
      local += WPc * lp + (1.f - WPc) * ln;
    }
  }
#pragma unroll
  for (int o = 32; o > 0; o >>= 1) local += __shfl_down(local, o, 64);
  if ((t & 63) == 0) red[t >> 6] = local;
  __syncthreads();
  if (t == 0) {
    float v = 0.f;
#pragma unroll
    for (int i = 0; i < 16; ++i) v += red[i];
    atomicAdd(accum, v);
    __threadfence();
    const int old = atomicAdd(ticket, 1);
    if (old == Bsz - 1) {
      const float tot = atomicAdd(accum, 0.f);  // atomic read via L2
      out[0] = tot / (float)(Bsz * Isz);
    }
  }
}

// ---------------------------------------------------------------------------
extern "C" void kernel_launch(void* const* d_in, const int* in_sizes, int n_in,
                              void* d_out, int out_size, void* d_ws,
                              size_t ws_size, hipStream_t stream) {
  const float* x = (const float*)d_in[0];          // [B,N,D] fp32
  const uint8_t* label = (const uint8_t*)d_in[1];  // [B,I,N] bool
  float* out = (float*)d_out;

  // Workspace: [gpos BN][gneg BN][inst BN i32][accum f32][ticket i32][xb BND bf16]
  float* gpos = (float*)d_ws;
  float* gneg = gpos + Bsz * Nsz;
  int* inst = (int*)(gneg + Bsz * Nsz);
  float* accum = (float*)(inst + Bsz * Nsz);
  int* ticket = (int*)(accum + 1);
  uint16_t* xb = (uint16_t*)(ticket + 1);

  prep_kernel<<<(Bsz * Nsz * Dsz) / (256 * 4), 256, 0, stream>>>(
      x, label, xb, inst, gpos, gneg, accum, ticket);

  dim3 grid(NPAIR, Bsz);
  sim_mfma<<<grid, 256, 0, stream>>>(xb, inst, gpos, gneg);

  fin_kernel<<<Bsz, 1024, 0, stream>>>(gpos, gneg, inst, accum, ticket, out);
}

// Round 5
// 112.265 us; speedup vs baseline: 1.2104x; 1.2104x over previous
//
#include <hip/hip_runtime.h>
#include <stdint.h>

// Problem constants: B=4, I=32, N=4096, D=64, TEM=1.0, WP=0.5
#define Bsz 4
#define Isz 32
#define Nsz 4096
#define Dsz 64
#define WPc 0.5f
#define ALPHA 1.2011224087864498f  // sqrt(log2(e)): folds 1/ln2 into the data
#define LN2 0.69314718055994531f

typedef __attribute__((ext_vector_type(8))) short short8;   // 8 bf16
typedef __attribute__((ext_vector_type(4))) float floatx4;  // MFMA C/D

__device__ inline uint16_t f2bf(float f) {
  uint32_t u = __float_as_uint(f);
  u += 0x7fffu + ((u >> 16) & 1u);  // RNE
  return (uint16_t)(u >> 16);
}

// exp2 via the raw v_exp_f32 instruction; same op in both kernels so the
// negtot - negsub subtraction cancels bit-exactly.
__device__ inline float exp2_raw(float f) { return __builtin_amdgcn_exp2f(f); }

// ---------------------------------------------------------------------------
// Kernel 1: convert x -> bf16(ALPHA*x); zero negtot / accum / ticket.
// ---------------------------------------------------------------------------
__global__ __launch_bounds__(256) void prep_kernel(
    const float* __restrict__ x, uint16_t* __restrict__ xb,
    float* __restrict__ negtot, float* __restrict__ accum,
    int* __restrict__ ticket) {
  const int t = threadIdx.x;
  const int blk = blockIdx.x;
  const int idx4 = (blk * 256 + t) * 4;
  const float4 v = *(const float4*)(x + idx4);
  ushort4 o;
  o.x = f2bf(v.x * ALPHA);
  o.y = f2bf(v.y * ALPHA);
  o.z = f2bf(v.z * ALPHA);
  o.w = f2bf(v.w * ALPHA);
  *(ushort4*)(xb + idx4) = o;
  if (blk < 64) {
    const int p = blk * 256 + t;  // 0..16383 rows
    negtot[p] = 0.f;
    if (p == 0) {
      accum[0] = 0.f;
      ticket[0] = 0;
    }
  }
}

// ---------------------------------------------------------------------------
// Kernel 2 (A): unconditional row sums of exp(sim) over ALL columns.
// 128x128 tile per block, fragments direct from L2-resident bf16.
// No LDS, no barriers, no instance logic. acc holds sim' = log2e * sim;
// exp2(acc) = exp(sim).  C/D layout: col = lane&15, row = (lane>>4)*4 + reg.
// ---------------------------------------------------------------------------
__global__ __launch_bounds__(256, 4) void rowsum_kernel(
    const uint16_t* __restrict__ xb, float* __restrict__ negtot) {
  const int t = threadIdx.x;
  const int lane = t & 63;
  const int w = t >> 6;
  const int quad = lane >> 4;
  const int l15 = lane & 15;

  const int b = blockIdx.y;
  const int row0 = (blockIdx.x >> 5) * 128;
  const int col0 = (blockIdx.x & 31) * 128;
  const size_t bN = (size_t)b * Nsz;
  const uint16_t* xbB = xb + bN * Dsz;
  const int wrow0 = row0 + w * 32;

  floatx4 acc[2][8];
#pragma unroll
  for (int rt = 0; rt < 2; ++rt)
#pragma unroll
    for (int ct = 0; ct < 8; ++ct) acc[rt][ct] = (floatx4){0.f, 0.f, 0.f, 0.f};

#pragma unroll
  for (int kh = 0; kh < 2; ++kh) {
    const int ko = quad * 8 + kh * 32;
    short8 af[2], bfr[8];
#pragma unroll
    for (int rt = 0; rt < 2; ++rt)
      af[rt] = *(const short8*)(xbB + (size_t)(wrow0 + rt * 16 + l15) * Dsz + ko);
#pragma unroll
    for (int ct = 0; ct < 8; ++ct)
      bfr[ct] = *(const short8*)(xbB + (size_t)(col0 + ct * 16 + l15) * Dsz + ko);
#pragma unroll
    for (int ct = 0; ct < 8; ++ct)
#pragma unroll
      for (int rt = 0; rt < 2; ++rt)
        acc[rt][ct] = __builtin_amdgcn_mfma_f32_16x16x32_bf16(af[rt], bfr[ct],
                                                              acc[rt][ct], 0, 0, 0);
  }

  // Slim epilogue: per row, sum exp2(acc) over this lane's 8 cols, reduce
  // over the 16 l15 lanes, one global atomic per row.
#pragma unroll
  for (int rt = 0; rt < 2; ++rt) {
    float ng[4] = {0.f, 0.f, 0.f, 0.f};
#pragma unroll
    for (int ct = 0; ct < 8; ++ct) {
      const floatx4 v = acc[rt][ct];
#pragma unroll
      for (int r = 0; r < 4; ++r) ng[r] += exp2_raw(v[r]);
    }
#pragma unroll
    for (int r = 0; r < 4; ++r) {
      float g = ng[r];
#pragma unroll
      for (int m = 1; m < 16; m <<= 1) g += __shfl_xor(g, m, 64);
      if (l15 == 0)
        atomicAdd(&negtot[bN + wrow0 + rt * 16 + quad * 4 + r], g);
    }
  }
}

// ---------------------------------------------------------------------------
// Kernel 3 (B): per-instance Gram + finalize. One block per (b,i).
// Membership from the label row (4096 bytes). Computes
//   pos      = sum over same-instance pairs of (s-1)^2
//   negsub[p]= sum over same-instance cols of exp(sim) (bit-identical to A)
// then per row: log(negtot[p]-negsub), reduces to the instance contribution,
// atomicAdds into accum; last block (ticket) writes the scalar output.
// ---------------------------------------------------------------------------
__global__ __launch_bounds__(256) void gram_kernel(
    const uint16_t* __restrict__ xb, const uint8_t* __restrict__ label,
    const float* __restrict__ negtot, float* __restrict__ accum,
    int* __restrict__ ticket, float* __restrict__ out) {
  __shared__ int list[1024];
  __shared__ int scnt;
  __shared__ float sPos[4];
  __shared__ float sLn[4];

  const int t = threadIdx.x;
  const int lane = t & 63;
  const int w = t >> 6;
  const int quad = lane >> 4;
  const int l15 = lane & 15;
  const int i = blockIdx.x;
  const int b = blockIdx.y;
  const size_t bN = (size_t)b * Nsz;
  const uint16_t* xbB = xb + bN * Dsz;

  if (t == 0) scnt = 0;
  __syncthreads();
  // membership: 16 label bytes per thread
  {
    const uint4 lv = ((const uint4*)(label + ((size_t)b * Isz + i) * Nsz))[t];
    const uint32_t words[4] = {lv.x, lv.y, lv.z, lv.w};
#pragma unroll
    for (int jw = 0; jw < 4; ++jw)
#pragma unroll
      for (int jb = 0; jb < 4; ++jb) {
        if ((words[jw] >> (jb * 8)) & 0xff) {
          const int idx = atomicAdd(&scnt, 1);
          if (idx < 1024) list[idx] = t * 16 + jw * 4 + jb;
        }
      }
  }
  __syncthreads();
  const int cnt = scnt;

  float pos = 0.f, lns = 0.f;
  if (cnt >= 5) {
    const int nch = (cnt + 127) >> 7;
    for (int rc = 0; rc < nch; ++rc) {
      float ngrow[2][4] = {{0.f, 0.f, 0.f, 0.f}, {0.f, 0.f, 0.f, 0.f}};
      for (int cc = 0; cc < nch; ++cc) {
        floatx4 acc[2][8];
#pragma unroll
        for (int rt = 0; rt < 2; ++rt)
#pragma unroll
          for (int ct = 0; ct < 8; ++ct) acc[rt][ct] = (floatx4){0.f, 0.f, 0.f, 0.f};
#pragma unroll
        for (int kh = 0; kh < 2; ++kh) {
          const int ko = quad * 8 + kh * 32;
          short8 af[2], bfr[8];
#pragma unroll
          for (int rt = 0; rt < 2; ++rt) {
            int ridx = rc * 128 + w * 32 + rt * 16 + l15;
            ridx = ridx < cnt ? ridx : cnt - 1;
            af[rt] = *(const short8*)(xbB + (size_t)list[ridx] * Dsz + ko);
          }
#pragma unroll
          for (int ct = 0; ct < 8; ++ct) {
            int cidx = cc * 128 + ct * 16 + l15;
            cidx = cidx < cnt ? cidx : cnt - 1;
            bfr[ct] = *(const short8*)(xbB + (size_t)list[cidx] * Dsz + ko);
          }
#pragma unroll
          for (int ct = 0; ct < 8; ++ct)
#pragma unroll
            for (int rt = 0; rt < 2; ++rt)
              acc[rt][ct] = __builtin_amdgcn_mfma_f32_16x16x32_bf16(
                  af[rt], bfr[ct], acc[rt][ct], 0, 0, 0);
        }
        // masked epilogue
#pragma unroll
        for (int rt = 0; rt < 2; ++rt) {
          const int rbase = rc * 128 + w * 32 + rt * 16 + quad * 4;
#pragma unroll
          for (int ct = 0; ct < 8; ++ct) {
            const bool cv = (cc * 128 + ct * 16 + l15) < cnt;
            const floatx4 v = acc[rt][ct];
#pragma unroll
            for (int r = 0; r < 4; ++r) {
              const bool ok = cv && (rbase + r < cnt);
              const float s = v[r];
              const float d = __builtin_fmaf(s, LN2, -1.f);  // true s - 1
              pos += ok ? d * d : 0.f;
              ngrow[rt][r] += ok ? exp2_raw(s) : 0.f;  // bit-matches kernel A
            }
          }
        }
      }
      // per-row: subtract from total, log, accumulate
#pragma unroll
      for (int rt = 0; rt < 2; ++rt)
#pragma unroll
        for (int r = 0; r < 4; ++r) {
          float g = ngrow[rt][r];
#pragma unroll
          for (int m = 1; m < 16; m <<= 1) g += __shfl_xor(g, m, 64);
          const int ridx = rc * 128 + w * 32 + rt * 16 + quad * 4 + r;
          if (l15 == 0 && ridx < cnt) {
            const float nf = negtot[bN + list[ridx]] - g;
            lns += __logf(fmaxf(nf, 1e-30f));
          }
        }
    }
    // block reduction
#pragma unroll
    for (int m = 1; m < 64; m <<= 1) {
      pos += __shfl_xor(pos, m, 64);
      lns += __shfl_xor(lns, m, 64);
    }
    if (lane == 0) {
      sPos[w] = pos;
      sLn[w] = lns;
    }
    __syncthreads();
    if (t == 0) {
      const float pt = sPos[0] + sPos[1] + sPos[2] + sPos[3];
      const float lt = sLn[0] + sLn[1] + sLn[2] + sLn[3];
      const float c = (float)cnt;
      const float contrib = WPc * pt / (c * c) + (1.f - WPc) * lt / c;
      atomicAdd(accum, contrib);
    }
  }
  if (t == 0) {
    __threadfence();
    const int old = atomicAdd(ticket, 1);
    if (old == Bsz * Isz - 1) {
      const float tot = atomicAdd(accum, 0.f);  // atomic read sees all adds
      out[0] = tot / (float)(Bsz * Isz);
    }
  }
}

// ---------------------------------------------------------------------------
extern "C" void kernel_launch(void* const* d_in, const int* in_sizes, int n_in,
                              void* d_out, int out_size, void* d_ws,
                              size_t ws_size, hipStream_t stream) {
  const float* x = (const float*)d_in[0];          // [B,N,D] fp32
  const uint8_t* label = (const uint8_t*)d_in[1];  // [B,I,N] bool
  float* out = (float*)d_out;

  // Workspace: [xb 1M bf16 (2MB, 16B-aligned at 0)][negtot BN f32][accum][ticket]
  uint16_t* xb = (uint16_t*)d_ws;
  float* negtot = (float*)(xb + (size_t)Bsz * Nsz * Dsz);
  float* accum = negtot + Bsz * Nsz;
  int* ticket = (int*)(accum + 1);

  prep_kernel<<<(Bsz * Nsz * Dsz) / (256 * 4), 256, 0, stream>>>(
      x, xb, negtot, accum, ticket);

  dim3 gridA(1024, Bsz);  // 32x32 tiles of 128x128
  rowsum_kernel<<<gridA, 256, 0, stream>>>(xb, negtot);

  dim3 gridB(Isz, Bsz);
  gram_kernel<<<gridB, 256, 0, stream>>>(xb, label, negtot, accum, ticket, out);
}